// Round 6
// baseline (289.060 us; speedup 1.0000x reference)
//
#include <hip/hip_runtime.h>

typedef __attribute__((ext_vector_type(8))) short short8;
typedef __attribute__((ext_vector_type(4))) float f32x4;

#define MFMA16(a, b, c) __builtin_amdgcn_mfma_f32_16x16x32_bf16(a, b, c, 0, 0, 0)

// B=4, S=2048, D=1024, H=16, HD=64
#define SEQ 2048
#define DIM 1024
#define NH 16
#define HD 64
#define LOG2E 1.4426950408889634f

__device__ __forceinline__ ushort f2bf(float f) {
  union { float f; unsigned u; } v; v.f = f;
  unsigned r = (v.u + 0x7FFFu + ((v.u >> 16) & 1u)) >> 16;
  return (ushort)r;
}

// 1-instruction bf16 round (RNE) via packed convert
__device__ __forceinline__ ushort bf1(float f) {
  unsigned r;
  asm("v_cvt_pk_bf16_f32 %0, %1, %2" : "=v"(r) : "v"(f), "v"(f));
  return (ushort)(r & 0xffffu);
}

__device__ __forceinline__ float exp2fn(float x) {
#if __has_builtin(__builtin_amdgcn_exp2f)
  return __builtin_amdgcn_exp2f(x);
#else
  return exp2f(x);
#endif
}

// ---------------- prep: a{q,k,v} = bf16(inputs + pos_emb) ----------------
__global__ __launch_bounds__(256) void prep_a(
    const float* __restrict__ x, const float* __restrict__ pq,
    const float* __restrict__ pk, const float* __restrict__ pv,
    ushort* __restrict__ aq, ushort* __restrict__ ak, ushort* __restrict__ av) {
  int i = (blockIdx.x * 256 + threadIdx.x) * 4;
  int pi = i & (SEQ * DIM - 1);
  float4 xv = *(const float4*)(x + i);
  float4 q4 = *(const float4*)(pq + pi);
  float4 k4 = *(const float4*)(pk + pi);
  float4 v4 = *(const float4*)(pv + pi);
  ushort4 o;
  o.x = f2bf(xv.x + q4.x); o.y = f2bf(xv.y + q4.y);
  o.z = f2bf(xv.z + q4.z); o.w = f2bf(xv.w + q4.w);
  *(ushort4*)(aq + i) = o;
  o.x = f2bf(xv.x + k4.x); o.y = f2bf(xv.y + k4.y);
  o.z = f2bf(xv.z + k4.z); o.w = f2bf(xv.w + k4.w);
  *(ushort4*)(ak + i) = o;
  o.x = f2bf(xv.x + v4.x); o.y = f2bf(xv.y + v4.y);
  o.z = f2bf(xv.z + v4.z); o.w = f2bf(xv.w + v4.w);
  *(ushort4*)(av + i) = o;
}

// ---------------- prep: W [K=1024][N=1024] fp32 -> Wt [N][K] bf16 ----------------
__global__ __launch_bounds__(256) void transpose_w(
    const float* __restrict__ src, ushort* __restrict__ dst) {
  __shared__ float t[32][33];
  int tx = threadIdx.x & 31, ty = threadIdx.x >> 5;
  int x0 = blockIdx.x * 32, y0 = blockIdx.y * 32;
#pragma unroll
  for (int j = 0; j < 32; j += 8) t[ty + j][tx] = src[(size_t)(y0 + ty + j) * DIM + x0 + tx];
  __syncthreads();
#pragma unroll
  for (int j = 0; j < 32; j += 8)
    dst[(size_t)(x0 + ty + j) * DIM + y0 + tx] = f2bf(t[tx][ty + j]);
}

// ---------------- GEMM: C[8192x1024] = A[8192x1024] * Bt[1024x1024]^T ----------------
// MODE 0: out bf16 scattered to [B,H,S,HD], value = (acc+bias)*scale
// MODE 1: out fp32 row-major [8192x1024], value = acc+bias
// MODE 2: out bf16 scattered to [B,H,HD,S] (V transposed), value = acc+bias
template <int MODE>
__global__ __launch_bounds__(256) void gemm128(
    const ushort* __restrict__ A, const ushort* __restrict__ Bt,
    const float* __restrict__ bias, void* __restrict__ outp, float scale) {
  constexpr int K = 1024, LDA = 40;
  __shared__ __align__(16) ushort As[128 * LDA];
  __shared__ __align__(16) ushort Bs[128 * LDA];
  const int tid = threadIdx.x;
  const int wave = tid >> 6, lane = tid & 63;
  const int wr = wave >> 1, wc = wave & 1;
  const int g = lane >> 4, l15 = lane & 15;
  const int bm = blockIdx.x, bn = blockIdx.y;
  const int r0 = tid >> 2, c0 = (tid & 3) * 8;
  const ushort* Ap = A + (size_t)(bm * 128 + r0) * K + c0;
  const ushort* Bp = Bt + (size_t)(bn * 128 + r0) * K + c0;
  f32x4 acc[4][4] = {};

  uint4 ra0 = *(const uint4*)(Ap);
  uint4 ra1 = *(const uint4*)(Ap + (size_t)64 * K);
  uint4 rb0 = *(const uint4*)(Bp);
  uint4 rb1 = *(const uint4*)(Bp + (size_t)64 * K);

  for (int kt = 0; kt < K; kt += 32) {
    __syncthreads();
    *(uint4*)&As[r0 * LDA + c0] = ra0;
    *(uint4*)&As[(r0 + 64) * LDA + c0] = ra1;
    *(uint4*)&Bs[r0 * LDA + c0] = rb0;
    *(uint4*)&Bs[(r0 + 64) * LDA + c0] = rb1;
    __syncthreads();
    if (kt + 32 < K) {
      ra0 = *(const uint4*)(Ap + kt + 32);
      ra1 = *(const uint4*)(Ap + (size_t)64 * K + kt + 32);
      rb0 = *(const uint4*)(Bp + kt + 32);
      rb1 = *(const uint4*)(Bp + (size_t)64 * K + kt + 32);
    }
    short8 af[4], bfr[4];
#pragma unroll
    for (int m = 0; m < 4; ++m)
      af[m] = *(const short8*)&As[(wr * 64 + m * 16 + l15) * LDA + g * 8];
#pragma unroll
    for (int n = 0; n < 4; ++n)
      bfr[n] = *(const short8*)&Bs[(wc * 64 + n * 16 + l15) * LDA + g * 8];
#pragma unroll
    for (int m = 0; m < 4; ++m)
#pragma unroll
      for (int n = 0; n < 4; ++n) acc[m][n] = MFMA16(af[m], bfr[n], acc[m][n]);
  }

#pragma unroll
  for (int m = 0; m < 4; ++m) {
    int row = bm * 128 + wr * 64 + m * 16 + g * 4;
#pragma unroll
    for (int n = 0; n < 4; ++n) {
      int col = bn * 128 + wc * 64 + n * 16 + l15;
      float bv = bias[col];
#pragma unroll
      for (int j = 0; j < 4; ++j) {
        float v = (acc[m][n][j] + bv) * scale;
        int r = row + j;
        if (MODE == 0) {
          int b = r >> 11, s = r & (SEQ - 1), h = col >> 6, hd = col & (HD - 1);
          ((ushort*)outp)[((size_t)((b * NH + h) * SEQ + s)) * HD + hd] = f2bf(v);
        } else if (MODE == 2) {
          int b = r >> 11, s = r & (SEQ - 1), h = col >> 6, hd = col & (HD - 1);
          ((ushort*)outp)[((size_t)((b * NH + h) * HD + hd)) * SEQ + s] = f2bf(v);
        } else {
          ((float*)outp)[(size_t)r * DIM + col] = v;
        }
      }
    }
  }
}

// ---------------- flash attention v6: single-barrier dbuf + XOR-swizzled K/V ----
// grid 1024 = 16 q-tiles x 64 bh (XCD-swizzled). 4 waves; each wave owns 32 q-rows.
// Q as A-operand, K as B-operand (verified layout). No-max exp2 softmax (verified).
// K/V LDS: [2][64 rows][8 chunks of 8 ushorts], chunk ^= (row&7) on BOTH write and
// read (bijective swizzle => identical dataflow, conflict-free, no padding).
__global__ __launch_bounds__(256) void attn6(
    const ushort* __restrict__ Q, const ushort* __restrict__ K,
    const ushort* __restrict__ VT, const float* __restrict__ abias,
    const float* __restrict__ kvbias, ushort* __restrict__ X) {
  constexpr int LDP = 72;
  constexpr int NT = SEQ / 64;
  __shared__ __align__(16) ushort Ks[2][64 * 64];    // [buf][key][d]  (swizzled)
  __shared__ __align__(16) ushort Vs[2][64 * 64];    // [buf][d][key]  (swizzled)
  __shared__ __align__(16) ushort Ps[4][32 * LDP];   // per-wave [q_local][key]
  const int tid = threadIdx.x;
  const int w = tid >> 6, lane = tid & 63, g = lane >> 4, l15 = lane & 15;
  const int px = blockIdx.x;
  const int qt = (px & 7) | ((px >> 9) << 3);   // bijective XCD swizzle
  const int bh = (px >> 3) & 63;
  const int b = bh >> 4, h = bh & (NH - 1);
  const int q0 = qt * 128;

  // Q fragments as A-operand: row = l15, k = c*32 + g*8 (+i)
  short8 qf[2][2];
#pragma unroll
  for (int sub = 0; sub < 2; ++sub) {
    const ushort* qp = Q + ((size_t)bh * SEQ + q0 + w * 32 + sub * 16 + l15) * HD;
#pragma unroll
    for (int c = 0; c < 2; ++c) qf[sub][c] = *(const short8*)(qp + c * 32 + g * 8);
  }

  f32x4 o[2][4] = {};
  float l_lane[2][4] = {};

  // staging: row sr, two 8-ushort chunks c0, c0+1; swizzle chunk ^= (sr&7)
  const int sr = tid >> 2, sc0 = (tid & 3) * 2;
  const int wofs0 = sr * 64 + ((sc0 ^ (sr & 7)) * 8);
  const int wofs1 = sr * 64 + (((sc0 + 1) ^ (sr & 7)) * 8);
  const int scc = (tid & 3) * 16;
  const ushort* Kp = K + (size_t)bh * SEQ * HD;    // [key][d]
  const ushort* Vp = VT + (size_t)bh * HD * SEQ;   // [d][key]
  const float* abp = abias + (size_t)q0 * SEQ;
  const float* kvp = kvbias + b * SEQ;

  // read-side swizzled chunk offsets (row & 7 == l15 & 7 for rows ct*16+l15)
  const int rx = l15 & 7;
  const int rc0 = (g ^ rx) * 8;        // cols g*8..+7
  const int rc1 = ((4 | g) ^ rx) * 8;  // cols 32+g*8..+7

  // prologue: load tile 0, stage into buf 0
  uint4 ka = *(const uint4*)(Kp + (size_t)sr * HD + scc);
  uint4 kb = *(const uint4*)(Kp + (size_t)sr * HD + scc + 8);
  uint4 va = *(const uint4*)(Vp + (size_t)sr * SEQ + scc);
  uint4 vb = *(const uint4*)(Vp + (size_t)sr * SEQ + scc + 8);
  *(uint4*)&Ks[0][wofs0] = ka;
  *(uint4*)&Ks[0][wofs1] = kb;
  *(uint4*)&Vs[0][wofs0] = va;
  *(uint4*)&Vs[0][wofs1] = vb;
  __syncthreads();

  for (int kt = 0; kt < NT; ++kt) {
    const int k0 = kt * 64;
    const int cur = kt & 1;

    // issue this tile's bias loads first (consumed in softmax below)
    float bkv[4];
#pragma unroll
    for (int ct = 0; ct < 4; ++ct) bkv[ct] = kvp[k0 + ct * 16 + l15];
    float abf[2][4][4];
#pragma unroll
    for (int sub = 0; sub < 2; ++sub)
#pragma unroll
      for (int j = 0; j < 4; ++j) {
        const float* abr = abp + (size_t)(w * 32 + sub * 16 + 4 * g + j) * SEQ + k0 + l15;
#pragma unroll
        for (int ct = 0; ct < 4; ++ct) abf[sub][ct][j] = abr[ct * 16];
      }

    // issue next-tile global loads (drain under this tile's full compute)
    if (kt + 1 < NT) {
      ka = *(const uint4*)(Kp + (size_t)(k0 + 64 + sr) * HD + scc);
      kb = *(const uint4*)(Kp + (size_t)(k0 + 64 + sr) * HD + scc + 8);
      va = *(const uint4*)(Vp + (size_t)sr * SEQ + k0 + 64 + scc);
      vb = *(const uint4*)(Vp + (size_t)sr * SEQ + k0 + 64 + scc + 8);
    }

    // S = Q K^T : rows q (D: 4g+j), cols key (D: l15). 2 subtiles x 4 key-chunks.
    f32x4 s4[2][4];
    __builtin_amdgcn_s_setprio(1);
#pragma unroll
    for (int ct = 0; ct < 4; ++ct) {
      const int rk = (ct * 16 + l15) * 64;
      short8 kf0 = *(const short8*)&Ks[cur][rk + rc0];
      short8 kf1 = *(const short8*)&Ks[cur][rk + rc1];
#pragma unroll
      for (int sub = 0; sub < 2; ++sub) {
        f32x4 z = {0.f, 0.f, 0.f, 0.f};
        f32x4 t = MFMA16(qf[sub][0], kf0, z);
        s4[sub][ct] = MFMA16(qf[sub][1], kf1, t);
      }
    }
    __builtin_amdgcn_s_setprio(0);

    // no-max softmax in exp2 domain; per-lane l partials (no in-loop reductions)
#pragma unroll
    for (int sub = 0; sub < 2; ++sub) {
      float p[4][4];
#pragma unroll
      for (int ct = 0; ct < 4; ++ct)
#pragma unroll
        for (int j = 0; j < 4; ++j)
          p[ct][j] = exp2fn(fmaf(abf[sub][ct][j] + bkv[ct], LOG2E, s4[sub][ct][j]));
#pragma unroll
      for (int j = 0; j < 4; ++j)
        l_lane[sub][j] += (p[0][j] + p[1][j]) + (p[2][j] + p[3][j]);
#pragma unroll
      for (int ct = 0; ct < 4; ++ct)
#pragma unroll
        for (int j = 0; j < 4; ++j)
          Ps[w][(sub * 16 + 4 * g + j) * LDP + ct * 16 + l15] = bf1(p[ct][j]);
    }

    // wave-private P ready
    asm volatile("s_waitcnt lgkmcnt(0)" ::: "memory");
    __builtin_amdgcn_sched_barrier(0);

    // O += P V  (P as A: row=l15 within sub-block; V^T as B: col=l15=d)
    short8 pa[2][2];
#pragma unroll
    for (int sub = 0; sub < 2; ++sub)
#pragma unroll
      for (int ks = 0; ks < 2; ++ks)
        pa[sub][ks] = *(const short8*)&Ps[w][(sub * 16 + l15) * LDP + ks * 32 + g * 8];
    __builtin_amdgcn_s_setprio(1);
#pragma unroll
    for (int ctd = 0; ctd < 4; ++ctd) {
      const int rv = (ctd * 16 + l15) * 64;
      short8 vf0 = *(const short8*)&Vs[cur][rv + rc0];
      short8 vf1 = *(const short8*)&Vs[cur][rv + rc1];
#pragma unroll
      for (int sub = 0; sub < 2; ++sub) {
        o[sub][ctd] = MFMA16(pa[sub][0], vf0, o[sub][ctd]);
        o[sub][ctd] = MFMA16(pa[sub][1], vf1, o[sub][ctd]);
      }
    }
    __builtin_amdgcn_s_setprio(0);

    // stage next tile into the alternate buffer; one barrier per tile
    if (kt + 1 < NT) {
      const int nxt = cur ^ 1;
      *(uint4*)&Ks[nxt][wofs0] = ka;
      *(uint4*)&Ks[nxt][wofs1] = kb;
      *(uint4*)&Vs[nxt][wofs0] = va;
      *(uint4*)&Vs[nxt][wofs1] = vb;
      __syncthreads();
    }
  }

  // one final l reduction per row (16-lane l15 group), then normalize + write
#pragma unroll
  for (int sub = 0; sub < 2; ++sub) {
    float inv[4];
#pragma unroll
    for (int j = 0; j < 4; ++j) {
      float l = l_lane[sub][j];
      l += __shfl_xor(l, 1);
      l += __shfl_xor(l, 2);
      l += __shfl_xor(l, 4);
      l += __shfl_xor(l, 8);
      inv[j] = 1.0f / l;
    }
#pragma unroll
    for (int ctd = 0; ctd < 4; ++ctd)
#pragma unroll
      for (int j = 0; j < 4; ++j) {
        size_t row = (size_t)b * SEQ + q0 + w * 32 + sub * 16 + 4 * g + j;
        X[row * DIM + h * HD + ctd * 16 + l15] = bf1(o[sub][ctd][j] * inv[j]);
      }
  }
}

extern "C" void kernel_launch(void* const* d_in, const int* in_sizes, int n_in,
                              void* d_out, int out_size, void* d_ws, size_t ws_size,
                              hipStream_t stream) {
  const float* inputs_q = (const float*)d_in[0];
  const float* pos_q = (const float*)d_in[1];
  const float* pos_k = (const float*)d_in[2];
  const float* pos_v = (const float*)d_in[3];
  const float* abias = (const float*)d_in[4];
  const float* kvbias = (const float*)d_in[5];
  const float* wq = (const float*)d_in[6];
  const float* bq = (const float*)d_in[7];
  const float* wk = (const float*)d_in[8];
  const float* bk = (const float*)d_in[9];
  const float* wv = (const float*)d_in[10];
  const float* bv = (const float*)d_in[11];
  const float* wo = (const float*)d_in[12];
  const float* bo = (const float*)d_in[13];

  char* ws = (char*)d_ws;
  const size_t MB = 1ull << 20;
  ushort* wqT = (ushort*)(ws + 0 * MB);
  ushort* wkT = (ushort*)(ws + 2 * MB);
  ushort* wvT = (ushort*)(ws + 4 * MB);
  ushort* woT = (ushort*)(ws + 6 * MB);
  ushort* aq = (ushort*)(ws + 8 * MB);
  ushort* ak = (ushort*)(ws + 24 * MB);
  ushort* av = (ushort*)(ws + 40 * MB);
  ushort* Qb = (ushort*)(ws + 56 * MB);
  ushort* Kb = (ushort*)(ws + 72 * MB);
  ushort* VTb = (ushort*)(ws + 88 * MB);
  ushort* Xb = (ushort*)(ws + 8 * MB);  // alias aq (dead after Q-GEMM)

  prep_a<<<8192, 256, 0, stream>>>(inputs_q, pos_q, pos_k, pos_v, aq, ak, av);
  dim3 tg(32, 32);
  transpose_w<<<tg, 256, 0, stream>>>(wq, wqT);
  transpose_w<<<tg, 256, 0, stream>>>(wk, wkT);
  transpose_w<<<tg, 256, 0, stream>>>(wv, wvT);
  transpose_w<<<tg, 256, 0, stream>>>(wo, woT);
  dim3 gg(64, 8);
  // Q pre-scaled by 1/sqrt(64) * log2(e): softmax runs in exp2 domain
  gemm128<0><<<gg, 256, 0, stream>>>(aq, wqT, bq, Qb, 0.125f * LOG2E);
  gemm128<0><<<gg, 256, 0, stream>>>(ak, wkT, bk, Kb, 1.0f);
  gemm128<2><<<gg, 256, 0, stream>>>(av, wvT, bv, VTb, 1.0f);
  attn6<<<1024, 256, 0, stream>>>(Qb, Kb, VTb, abias, kvbias, Xb);
  gemm128<1><<<gg, 256, 0, stream>>>(Xb, woT, bo, d_out, 1.0f);
}